// Round 9
// baseline (209.276 us; speedup 1.0000x reference)
//
#include <hip/hip_runtime.h>
#include <math.h>

#define T_DIM 2048
#define B_DIM 2
#define C_DIM 1024
#define H_DIM 16
#define D_DIM 64
#define M_DIM (T_DIM * B_DIM)   // 4096
// q scale with log2e folded in: attn computes P = exp2(S) directly.
#define SCALE_QL2 0.18033688f   // D^-0.5 * log2(e)

typedef short short8  __attribute__((ext_vector_type(8)));
typedef float f32x4   __attribute__((ext_vector_type(4)));
typedef float f32x16  __attribute__((ext_vector_type(16)));
typedef unsigned short ushort_t;

#if __has_builtin(__builtin_amdgcn_exp2f)
#define EXP2(x) __builtin_amdgcn_exp2f(x)
#else
#define EXP2(x) exp2f(x)
#endif

__device__ __forceinline__ unsigned short f2bf(float f) {
    unsigned int u = __builtin_bit_cast(unsigned int, f);
    u += 0x7FFFu + ((u >> 16) & 1u);           // round-to-nearest-even
    return (unsigned short)(u >> 16);
}

__device__ __forceinline__ void gl_lds16(const void* g, void* l) {
    __builtin_amdgcn_global_load_lds(
        (const __attribute__((address_space(1))) void*)g,
        (__attribute__((address_space(3))) void*)l, 16, 0, 0);
}

// ---------------------------------------------------------------------------
// prep: fused input conversion.
//   z<4 : transpose-cast w (k,n) fp32 -> w^T (n,k) bf16 (64x64 LDS tiles)
//   z==4: straight cast x fp32 -> bf16 (16384 els per block)
// ---------------------------------------------------------------------------
__global__ __launch_bounds__(256) void prep(
    const float* __restrict__ x,
    const float* __restrict__ wq, const float* __restrict__ wk,
    const float* __restrict__ wv, const float* __restrict__ wo,
    ushort_t* __restrict__ xb,
    ushort_t* __restrict__ wqkv_t, ushort_t* __restrict__ wo_t)
{
    __shared__ float tile[64][65];
    const int tid = threadIdx.x;
    const int z   = blockIdx.z;

    if (z == 4) {   // cast x
        const size_t base =
            ((size_t)(blockIdx.y * 16 + blockIdx.x)) * 16384 + (size_t)tid * 8;
#pragma unroll
        for (int j = 0; j < 8; ++j) {
            const size_t i = base + (size_t)j * 2048;
            const float4 v0 = *(const float4*)&x[i];
            const float4 v1 = *(const float4*)&x[i + 4];
            ushort_t o[8] = {f2bf(v0.x), f2bf(v0.y), f2bf(v0.z), f2bf(v0.w),
                             f2bf(v1.x), f2bf(v1.y), f2bf(v1.z), f2bf(v1.w)};
            *(uint4*)&xb[i] = *(uint4*)o;
        }
        return;
    }

    const int k0 = blockIdx.x * 64;
    const int n0 = blockIdx.y * 64;
    const float* src = (z == 0) ? wq : (z == 1) ? wk : (z == 2) ? wv : wo;
    ushort_t* dst = (z < 3) ? (wqkv_t + (size_t)z * C_DIM * C_DIM) : wo_t;

    const int r = tid >> 4;
    const int c = (tid & 15) * 4;
#pragma unroll
    for (int i = 0; i < 4; ++i) {
        const float4 v = *(const float4*)&src[(size_t)(k0 + r + i * 16) * C_DIM + n0 + c];
        *(float4*)&tile[r + i * 16][c] = v;
    }
    __syncthreads();
#pragma unroll
    for (int i = 0; i < 4; ++i) {
        const int r2 = r + i * 16;        // n-rel
        ushort4 o;
        o.x = f2bf(tile[c + 0][r2]); o.y = f2bf(tile[c + 1][r2]);
        o.z = f2bf(tile[c + 2][r2]); o.w = f2bf(tile[c + 3][r2]);
        *(ushort4*)&dst[(size_t)(n0 + r2) * C_DIM + k0 + c] = o;
    }
}

// ---------------------------------------------------------------------------
// QKV projection, bf16 MFMA. C[m,n] = xb[m,k] @ wt[n,k]^T, M=4096 N=3072
// K=1024. 128x128 tile, BK=32, 4 waves. Per-wave LDS-transpose epilogue ->
// coalesced dwordx4 stores. q scaled by D^-0.5*log2e. V written TRANSPOSED
// (bh,d,t) directly (v_transpose kernel fused away; correctness proven
// rounds 4-8).
// ---------------------------------------------------------------------------
__global__ __launch_bounds__(256) void qkv_mfma(
    const ushort_t* __restrict__ xb, const ushort_t* __restrict__ wt,
    ushort_t* __restrict__ q_ws, ushort_t* __restrict__ k_ws,
    ushort_t* __restrict__ v_ws /* (bh,d,t) */)
{
    __shared__ ushort_t lds[18432];      // 36,864 B
    ushort_t* As = lds;                  // [128*32]
    ushort_t* Bs = lds + 4096;           // [128*32]

    const int tid  = threadIdx.x;
    const int n0   = blockIdx.x * 128;   // 0..2944
    const int m0   = blockIdx.y * 128;
    const int w    = tid >> 6;
    const int lane = tid & 63;
    const int l16  = lane & 15;
    const int quad = lane >> 4;
    const int wm   = (w >> 1) * 64;
    const int wn   = (w & 1) * 64;

    const int o0 = tid * 8, o1 = o0 + 2048;
    const ushort_t* a0 = xb + (size_t)(m0 + (o0 >> 5)) * C_DIM + (o0 & 31);
    const ushort_t* a1 = xb + (size_t)(m0 + (o1 >> 5)) * C_DIM + (o1 & 31);
    const ushort_t* b0 = wt + (size_t)(n0 + (o0 >> 5)) * C_DIM + (o0 & 31);
    const ushort_t* b1 = wt + (size_t)(n0 + (o1 >> 5)) * C_DIM + (o1 & 31);

    f32x4 acc[4][4] = {};

    for (int k0 = 0; k0 < C_DIM; k0 += 32) {
        __syncthreads();
        gl_lds16(a0 + k0, As + o0);
        gl_lds16(a1 + k0, As + o1);
        gl_lds16(b0 + k0, Bs + o0);
        gl_lds16(b1 + k0, Bs + o1);
        __syncthreads();

        short8 af[4], bf[4];
#pragma unroll
        for (int mi = 0; mi < 4; ++mi)
            af[mi] = *(const short8*)&As[(wm + mi * 16 + l16) * 32 + quad * 8];
#pragma unroll
        for (int ni = 0; ni < 4; ++ni)
            bf[ni] = *(const short8*)&Bs[(wn + ni * 16 + l16) * 32 + quad * 8];
#pragma unroll
        for (int mi = 0; mi < 4; ++mi)
#pragma unroll
            for (int ni = 0; ni < 4; ++ni)
                acc[mi][ni] = __builtin_amdgcn_mfma_f32_16x16x32_bf16(
                    af[mi], bf[ni], acc[mi][ni], 0, 0, 0);
    }

    // ---- epilogue: wave-private LDS transpose, then coalesced stores ----
    __syncthreads();
    ushort_t* Ep = lds + w * 4608;         // 64 rows x 72 pitch

    const int mat = n0 >> 10;              // 0=q 1=k 2=v
    const int cb  = (n0 & 1023) + wn;
    const int h   = cb >> 6;
    const int rq  = lane >> 3;
    const int c8  = (lane & 7) * 8;

    if (mat == 2) {
        // V^T path: Ep[row = d (n_rel)][col = t_rel + 32*b], m_rel = 2*t_rel+b
#pragma unroll
        for (int mi = 0; mi < 4; ++mi)
#pragma unroll
            for (int ni = 0; ni < 4; ++ni)
#pragma unroll
                for (int r = 0; r < 4; ++r) {
                    const int mrel = mi * 16 + quad * 4 + r;
                    Ep[(ni * 16 + l16) * 72 + (mrel >> 1) + ((mrel & 1) << 5)] =
                        f2bf(acc[mi][ni][r]);
                }
        // wave-private region: lgkmcnt dependency only
        const int T0 = (m0 + wm) >> 1;
        const int b  = c8 >> 5;
        const int tr = c8 & 31;
#pragma unroll
        for (int p = 0; p < 8; ++p) {
            const int d = p * 8 + rq;
            const uint4 val = *(const uint4*)&Ep[d * 72 + c8];
            *(uint4*)&v_ws[((size_t)(b * H_DIM + h) * D_DIM + d) * T_DIM + T0 + tr] = val;
        }
        return;
    }

    ushort_t* dst = (mat == 0) ? q_ws : k_ws;
    const float sc = (mat == 0) ? SCALE_QL2 : 1.0f;

#pragma unroll
    for (int mi = 0; mi < 4; ++mi)
#pragma unroll
        for (int ni = 0; ni < 4; ++ni)
#pragma unroll
            for (int r = 0; r < 4; ++r)
                Ep[(mi * 16 + quad * 4 + r) * 72 + ni * 16 + l16] =
                    f2bf(acc[mi][ni][r] * sc);
    // wave-private region: lgkmcnt dependency only

#pragma unroll
    for (int p = 0; p < 8; ++p) {
        const int row = p * 8 + rq;
        const uint4 val = *(const uint4*)&Ep[row * 72 + c8];
        const int m = m0 + wm + row;
        const int t = m >> 1, b = m & 1;
        *(uint4*)&dst[((size_t)(b * H_DIM + h) * T_DIM + t) * D_DIM + c8] = val;
    }
}

// ---------------------------------------------------------------------------
// MFMA flash attention, 32x32x16, swapped QK^T, in-register softmax,
// IN-BLOCK SPLIT-K, register-light redesign (<=128 unified target):
//  - 256 threads / 4 waves: g = w>>1 k-half, wq = w&1 q-subtile (32 rows).
//    grid 32 bh x 32 q-tiles(64) = 1024 blocks x 4 waves = 4096 waves
//    = 4 waves/SIMD (fixes the 2048-wave grid limit of the round-3 body).
//  - Register cuts vs failed round-7 split-K (which spilled at 88 VGPR):
//    (a) K/V staging via gl_lds16 with XOR-PRE-SWIZZLED GLOBAL SOURCE
//        (linear LDS dest [64][64], read col ^= (row&7)<<4 in bytes; rows
//        0-7 cover all 32 banks once -> bank-optimal) -- kills 16 staging
//        VGPRs + pointer pairs;
//    (b) sequential half-tile processing (QK/exp2/pack/PV per 32-k half):
//        transient peak st(16) or wpk(8)+ap(8), not st(32)+wpk(16)+ap(16).
//  - max-free softmax => split exact: O = O0+O1, sum = sum0+sum1. g==1
//    writes f32 partials to LDS overlay (lane*33 pitch, 2-way free), g==0
//    combines + normalizes + stores. Combine logic correctness-proven r4-7.
//  - ones-MFMA row sums kept (sums the exact bf16 P the numerator uses).
//  - grid: x = bh -> XCD i gets bh === i (mod 8), 2 MB K/V per XCD L2. Keep.
//  - GO/NO-GO: VGPR_Count <= 128 and WRITE_SIZE ~8 MB. If spill: revert to
//    round-8 attn body (54 us, 96 VGPR, banked).
// ---------------------------------------------------------------------------
__global__ __launch_bounds__(256) void attn_mfma(
    const ushort_t* __restrict__ q, const ushort_t* __restrict__ k,
    const ushort_t* __restrict__ v, ushort_t* __restrict__ ctx)
{
    // 4 linear tiles of [64][64] bf16: Kh0 Kh1 Vh0 Vh1 (8 KB each, 32 KB).
    __shared__ __align__(16) ushort_t smem[16384];
    float* fl = (float*)smem;                  // combine overlay

    const int tid  = threadIdx.x;
    const int bh   = blockIdx.x;
    const int q0   = blockIdx.y * 64;
    const int w    = tid >> 6;          // 0..3
    const int g    = w >> 1;            // k-half [g*1024, g*1024+1024)
    const int wq   = w & 1;             // q-subtile
    const int lane = tid & 63;
    const int l32  = lane & 31;
    const int hi   = lane >> 5;

    const char* kB = (const char*)(k + (size_t)bh * T_DIM * D_DIM);
    const char* vB = (const char*)(v + (size_t)bh * D_DIM * T_DIM);

    // staging geometry: thread covers 16 B at tile row srow(+32), byte col scb
    const int srow = tid >> 3;                 // 0..31
    const int scb  = (tid & 7) << 4;           // 0..112
    const int sswz = scb ^ ((srow & 7) << 4);  // pre-swizzled source col

    // byte offsets into K (t,d) and V^T (d,t); advance per k-tile
    int ko[2][2], vo[2][2];
#pragma unroll
    for (int h = 0; h < 2; ++h)
#pragma unroll
        for (int c = 0; c < 2; ++c) {
            ko[h][c] = (h * 1024 + srow + c * 32) * 128 + sswz;
            vo[h][c] = (srow + c * 32) * 4096 + h * 2048 + sswz;
        }

    // Q rows q0 + 32*wq (+l32); 32x32x16 B-fragment layout.
    short8 qreg[4];
    {
        const ushort_t* qrow =
            q + ((size_t)bh * T_DIM + q0 + 32 * wq + l32) * D_DIM + hi * 8;
#pragma unroll
        for (int s = 0; s < 4; ++s)
            qreg[s] = *(const short8*)(qrow + s * 16);
    }

    short8 vones;
#pragma unroll
    for (int j = 0; j < 8; ++j) vones[j] = (short)0x3F80;

    f32x16 O0 = {}, O1 = {};      // O[q=32][d: tile 0/1] partial (k-half g)
    f32x16 Osum = {};             // partial row sums via ones-MFMA

    const int rsw = (l32 & 7) << 4;   // read-side swizzle (byte)

    for (int kt = 0; kt < 16; ++kt) {
        __syncthreads();
#pragma unroll
        for (int h = 0; h < 2; ++h)
#pragma unroll
            for (int c = 0; c < 2; ++c) {
                gl_lds16(kB + ko[h][c],
                         (char*)smem + h * 8192 + c * 4096 + (tid << 4));
                gl_lds16(vB + vo[h][c],
                         (char*)smem + 16384 + h * 8192 + c * 4096 + (tid << 4));
                ko[h][c] += 8192;     // 64 K-rows
                vo[h][c] += 128;      // 64 t-cols
            }
        __syncthreads();              // vmcnt drained by compiler before barrier

        const ushort_t* Kg = smem + g * 4096;
        const ushort_t* Vg = smem + 8192 + g * 4096;

#pragma unroll
        for (int half = 0; half < 2; ++half) {
            // S^T for k-rows half*32..+31: A = K rows (lane = k-pos), B = Q.
            f32x16 st = {};
            __builtin_amdgcn_s_setprio(1);
#pragma unroll
            for (int s = 0; s < 4; ++s) {
                const int cb = ((32 * s + 16 * hi) ^ rsw) >> 1;
                const short8 ak = *(const short8*)&Kg[(half * 32 + l32) * 64 + cb];
                st = __builtin_amdgcn_mfma_f32_32x32x16_bf16(ak, qreg[s], st, 0, 0, 0);
            }
            __builtin_amdgcn_s_setprio(0);

            // P = exp2(S^T) -> packed bf16 pairs (truncation via v_perm_b32)
            unsigned wpk[8];
#pragma unroll
            for (int i = 0; i < 8; ++i) {
                const float a0 = EXP2(st[2 * i]);
                const float a1 = EXP2(st[2 * i + 1]);
                wpk[i] = __builtin_amdgcn_perm(
                    __builtin_bit_cast(unsigned, a1),
                    __builtin_bit_cast(unsigned, a0), 0x07060302u);
            }

            // cross-half exchange -> 2 PV A-fragments; PV + row sums now
            short8 ap2[2];
#pragma unroll
            for (int pr = 0; pr < 2; ++pr) {
                unsigned x0 = wpk[4 * pr + 0], y0 = wpk[4 * pr + 2];
                unsigned x1 = wpk[4 * pr + 1], y1 = wpk[4 * pr + 3];
                asm("v_permlane32_swap_b32 %0, %1" : "+v"(x0), "+v"(y0));
                asm("v_permlane32_swap_b32 %0, %1" : "+v"(x1), "+v"(y1));
                uint4 fw = {x0, x1, y0, y1};
                ap2[pr] = __builtin_bit_cast(short8, fw);
            }

            __builtin_amdgcn_s_setprio(1);
#pragma unroll
            for (int pr = 0; pr < 2; ++pr) {
                const int s = half * 2 + pr;
                Osum = __builtin_amdgcn_mfma_f32_32x32x16_bf16(ap2[pr], vones, Osum, 0, 0, 0);
                const int cb = ((32 * s + 16 * hi) ^ rsw) >> 1;
                const short8 bv0 = *(const short8*)&Vg[l32 * 64 + cb];
                const short8 bv1 = *(const short8*)&Vg[(32 + l32) * 64 + cb];
                O0 = __builtin_amdgcn_mfma_f32_32x32x16_bf16(ap2[pr], bv0, O0, 0, 0, 0);
                O1 = __builtin_amdgcn_mfma_f32_32x32x16_bf16(ap2[pr], bv1, O1, 0, 0, 0);
            }
            __builtin_amdgcn_s_setprio(0);
        }
    }

    // ---- combine halves via LDS overlay, then normalize + store (g==0) ----
    __syncthreads();                       // all frag reads done before overlay
    float* pb = fl + wq * 2144 + lane * 33;        // 64 lanes x 33 f32, 2-way free
    float* sb = fl + wq * 2144 + 2112;             // 32 row sums
    if (g == 1) {
#pragma unroll
        for (int j = 0; j < 16; ++j) { pb[j] = O0[j]; pb[16 + j] = O1[j]; }
        if (l32 == 0) {
#pragma unroll
            for (int reg = 0; reg < 16; ++reg)
                sb[(reg & 3) + 8 * (reg >> 2) + 4 * hi] = Osum[reg];
        }
    }
    __syncthreads();
    if (g == 0) {
        const int b = bh >> 4;
        const int h = bh & 15;
#pragma unroll
        for (int reg = 0; reg < 16; ++reg) {
            const int qrel = (reg & 3) + 8 * (reg >> 2) + 4 * hi;
            const float inv = 1.0f / (Osum[reg] + sb[qrel]);
            const int row = q0 + 32 * wq + qrel;
            const size_t base = ((size_t)row * B_DIM + b) * C_DIM + h * 64 + l32;
            ctx[base]      = f2bf((O0[reg] + pb[reg])      * inv);
            ctx[base + 32] = f2bf((O1[reg] + pb[16 + reg]) * inv);
        }
    }
}

// ---------------------------------------------------------------------------
// Output projection, bf16 MFMA: out[m,n] = ctx[m,k] @ wo_t[n,k]^T + bo[n].
// ---------------------------------------------------------------------------
__global__ __launch_bounds__(256) void out_mfma(
    const ushort_t* __restrict__ ctx, const ushort_t* __restrict__ wot,
    const float* __restrict__ bo, float* __restrict__ out)
{
    __shared__ ushort_t As[128 * 32];
    __shared__ ushort_t Bs[64 * 32];

    const int tid  = threadIdx.x;
    const int n0   = blockIdx.x * 64;
    const int m0   = blockIdx.y * 128;
    const int w    = tid >> 6;
    const int lane = tid & 63;
    const int l16  = lane & 15;
    const int quad = lane >> 4;
    const int wm   = (w >> 1) * 64;
    const int wn   = (w & 1) * 32;

    const int o0 = tid * 8, o1 = o0 + 2048;
    const ushort_t* a0 = ctx + (size_t)(m0 + (o0 >> 5)) * C_DIM + (o0 & 31);
    const ushort_t* a1 = ctx + (size_t)(m0 + (o1 >> 5)) * C_DIM + (o1 & 31);
    const ushort_t* b0 = wot + (size_t)(n0 + (o0 >> 5)) * C_DIM + (o0 & 31);

    f32x4 acc[4][2] = {};

    for (int k0 = 0; k0 < C_DIM; k0 += 32) {
        __syncthreads();
        gl_lds16(a0 + k0, As + o0);
        gl_lds16(a1 + k0, As + o1);
        gl_lds16(b0 + k0, Bs + o0);
        __syncthreads();

        short8 af[4], bf[2];
#pragma unroll
        for (int mi = 0; mi < 4; ++mi)
            af[mi] = *(const short8*)&As[(wm + mi * 16 + l16) * 32 + quad * 8];
#pragma unroll
        for (int ni = 0; ni < 2; ++ni)
            bf[ni] = *(const short8*)&Bs[(wn + ni * 16 + l16) * 32 + quad * 8];
#pragma unroll
        for (int mi = 0; mi < 4; ++mi)
#pragma unroll
            for (int ni = 0; ni < 2; ++ni)
                acc[mi][ni] = __builtin_amdgcn_mfma_f32_16x16x32_bf16(
                    af[mi], bf[ni], acc[mi][ni], 0, 0, 0);
    }

#pragma unroll
    for (int ni = 0; ni < 2; ++ni) {
        const int n = n0 + wn + ni * 16 + l16;
        const float bias = bo[n];
#pragma unroll
        for (int mi = 0; mi < 4; ++mi) {
            const int mb = m0 + wm + mi * 16 + quad * 4;
#pragma unroll
            for (int r = 0; r < 4; ++r)
                out[(size_t)(mb + r) * C_DIM + n] = acc[mi][ni][r] + bias;
        }
    }
}

extern "C" void kernel_launch(void* const* d_in, const int* in_sizes, int n_in,
                              void* d_out, int out_size, void* d_ws, size_t ws_size,
                              hipStream_t stream)
{
    const float* x  = (const float*)d_in[0];
    const float* wq = (const float*)d_in[1];
    const float* wk = (const float*)d_in[2];
    const float* wv = (const float*)d_in[3];
    const float* wo = (const float*)d_in[4];
    const float* bo = (const float*)d_in[5];
    float* out = (float*)d_out;

    const size_t CC  = (size_t)C_DIM * C_DIM;          // 1.05M
    const size_t MC  = (size_t)M_DIM * C_DIM;          // 4.19M
    ushort_t* xb     = (ushort_t*)d_ws;
    ushort_t* wqkv_t = xb + MC;
    ushort_t* wo_t   = wqkv_t + 3 * CC;
    ushort_t* q_ws   = wo_t + CC;
    ushort_t* k_ws   = q_ws + MC;
    ushort_t* v_t    = k_ws + MC;                      // (bh,d,t) direct
    ushort_t* ctx    = v_t + MC;

    hipLaunchKernelGGL(prep, dim3(16, 16, 5), dim3(256), 0, stream,
                       x, wq, wk, wv, wo, xb, wqkv_t, wo_t);
    hipLaunchKernelGGL(qkv_mfma, dim3(24, 32), dim3(256), 0, stream,
                       xb, wqkv_t, q_ws, k_ws, v_t);
    hipLaunchKernelGGL(attn_mfma, dim3(32, 32), dim3(256), 0, stream,
                       q_ws, k_ws, v_t, ctx);
    hipLaunchKernelGGL(out_mfma, dim3(16, 32), dim3(256), 0, stream,
                       ctx, wo_t, bo, out);
}

// Round 11
// 190.246 us; speedup vs baseline: 1.1000x; 1.1000x over previous
//
#include <hip/hip_runtime.h>
#include <math.h>

#define T_DIM 2048
#define B_DIM 2
#define C_DIM 1024
#define H_DIM 16
#define D_DIM 64
#define M_DIM (T_DIM * B_DIM)   // 4096
// q scale with log2e folded in: attn computes P = exp2(S) directly.
#define SCALE_QL2 0.18033688f   // D^-0.5 * log2(e)

typedef short short8  __attribute__((ext_vector_type(8)));
typedef float f32x4   __attribute__((ext_vector_type(4)));
typedef float f32x16  __attribute__((ext_vector_type(16)));
typedef unsigned short ushort_t;

#if __has_builtin(__builtin_amdgcn_exp2f)
#define EXP2(x) __builtin_amdgcn_exp2f(x)
#else
#define EXP2(x) exp2f(x)
#endif

__device__ __forceinline__ unsigned short f2bf(float f) {
    unsigned int u = __builtin_bit_cast(unsigned int, f);
    u += 0x7FFFu + ((u >> 16) & 1u);           // round-to-nearest-even
    return (unsigned short)(u >> 16);
}

__device__ __forceinline__ void gl_lds16(const void* g, void* l) {
    __builtin_amdgcn_global_load_lds(
        (const __attribute__((address_space(1))) void*)g,
        (__attribute__((address_space(3))) void*)l, 16, 0, 0);
}

// ---------------------------------------------------------------------------
// SESSION LEDGER (why this exact configuration):
//  - This is the measured session-best (189.4 us, round 3 bench).
//  - attn: 32x32x16 swapped-QK^T, in-register softmax, 256 thr / 4 waves,
//    q-tile 128, grid (32 bh, 16 q): 55.6 us, 96 VGPR, 0 bank conflicts.
//  - v_transpose kept SEPARATE: fusing V^T into qkv's epilogue passed
//    correctness (r4-r9) but measured SLOWER overall (rest-of-pipeline
//    133.8 -> 143-149 us; conflicted scalar Ep writes + scattered 64B
//    global stores exceed the ~5 us kernel it deletes).
//  - Split-K attn (rounds 4-10): every variant either spilled to scratch
//    (allocator grants <= 88 VGPR vs ~130 demand at 512 thr or 36.9KB LDS)
//    or regressed (r9: staging conflicts at 128B pitch) or failed
//    correctness (r10 hybrid). Expected net gain vs this config is <= 5 us.
//    Do not reattempt without an offline refcheck harness.
//  - Bank-math worth remembering: pitch 72 ushorts = 36 words === 4 mod 32
//    rotates banks per row (0 conflicts measured); 128B-pitch rows alias
//    (row contributes nothing mod 32) -- the (row&7) XOR there leaves 4-way.
// ---------------------------------------------------------------------------

// ---------------------------------------------------------------------------
// prep: fused input conversion.
//   z<4 : transpose-cast w (k,n) fp32 -> w^T (n,k) bf16 (64x64 LDS tiles)
//   z==4: straight cast x fp32 -> bf16 (16384 els per block)
// ---------------------------------------------------------------------------
__global__ __launch_bounds__(256) void prep(
    const float* __restrict__ x,
    const float* __restrict__ wq, const float* __restrict__ wk,
    const float* __restrict__ wv, const float* __restrict__ wo,
    ushort_t* __restrict__ xb,
    ushort_t* __restrict__ wqkv_t, ushort_t* __restrict__ wo_t)
{
    __shared__ float tile[64][65];
    const int tid = threadIdx.x;
    const int z   = blockIdx.z;

    if (z == 4) {   // cast x
        const size_t base =
            ((size_t)(blockIdx.y * 16 + blockIdx.x)) * 16384 + (size_t)tid * 8;
#pragma unroll
        for (int j = 0; j < 8; ++j) {
            const size_t i = base + (size_t)j * 2048;
            const float4 v0 = *(const float4*)&x[i];
            const float4 v1 = *(const float4*)&x[i + 4];
            ushort_t o[8] = {f2bf(v0.x), f2bf(v0.y), f2bf(v0.z), f2bf(v0.w),
                             f2bf(v1.x), f2bf(v1.y), f2bf(v1.z), f2bf(v1.w)};
            *(uint4*)&xb[i] = *(uint4*)o;
        }
        return;
    }

    const int k0 = blockIdx.x * 64;
    const int n0 = blockIdx.y * 64;
    const float* src = (z == 0) ? wq : (z == 1) ? wk : (z == 2) ? wv : wo;
    ushort_t* dst = (z < 3) ? (wqkv_t + (size_t)z * C_DIM * C_DIM) : wo_t;

    const int r = tid >> 4;
    const int c = (tid & 15) * 4;
#pragma unroll
    for (int i = 0; i < 4; ++i) {
        const float4 v = *(const float4*)&src[(size_t)(k0 + r + i * 16) * C_DIM + n0 + c];
        *(float4*)&tile[r + i * 16][c] = v;
    }
    __syncthreads();
#pragma unroll
    for (int i = 0; i < 4; ++i) {
        const int r2 = r + i * 16;        // n-rel
        ushort4 o;
        o.x = f2bf(tile[c + 0][r2]); o.y = f2bf(tile[c + 1][r2]);
        o.z = f2bf(tile[c + 2][r2]); o.w = f2bf(tile[c + 3][r2]);
        *(ushort4*)&dst[(size_t)(n0 + r2) * C_DIM + k0 + c] = o;
    }
}

// ---------------------------------------------------------------------------
// QKV projection, bf16 MFMA. C[m,n] = xb[m,k] @ wt[n,k]^T, M=4096 N=3072
// K=1024. 128x128 tile, BK=32 (64B LDS row pitch; BK=64's 128B pitch measured
// -9us), 4 waves. Per-wave LDS-transpose epilogue -> coalesced dwordx4
// stores; q/k/v natural (bh,t,d), q scaled by D^-0.5*log2e.
// ---------------------------------------------------------------------------
__global__ __launch_bounds__(256) void qkv_mfma(
    const ushort_t* __restrict__ xb, const ushort_t* __restrict__ wt,
    ushort_t* __restrict__ q_ws, ushort_t* __restrict__ k_ws,
    ushort_t* __restrict__ v_ws)
{
    __shared__ ushort_t lds[18432];      // 36,864 B
    ushort_t* As = lds;                  // [128*32]
    ushort_t* Bs = lds + 4096;           // [128*32]

    const int tid  = threadIdx.x;
    const int n0   = blockIdx.x * 128;   // 0..2944
    const int m0   = blockIdx.y * 128;
    const int w    = tid >> 6;
    const int lane = tid & 63;
    const int l16  = lane & 15;
    const int quad = lane >> 4;
    const int wm   = (w >> 1) * 64;
    const int wn   = (w & 1) * 64;

    const int o0 = tid * 8, o1 = o0 + 2048;
    const ushort_t* a0 = xb + (size_t)(m0 + (o0 >> 5)) * C_DIM + (o0 & 31);
    const ushort_t* a1 = xb + (size_t)(m0 + (o1 >> 5)) * C_DIM + (o1 & 31);
    const ushort_t* b0 = wt + (size_t)(n0 + (o0 >> 5)) * C_DIM + (o0 & 31);
    const ushort_t* b1 = wt + (size_t)(n0 + (o1 >> 5)) * C_DIM + (o1 & 31);

    f32x4 acc[4][4] = {};

    for (int k0 = 0; k0 < C_DIM; k0 += 32) {
        __syncthreads();
        gl_lds16(a0 + k0, As + o0);
        gl_lds16(a1 + k0, As + o1);
        gl_lds16(b0 + k0, Bs + o0);
        gl_lds16(b1 + k0, Bs + o1);
        __syncthreads();

        short8 af[4], bf[4];
#pragma unroll
        for (int mi = 0; mi < 4; ++mi)
            af[mi] = *(const short8*)&As[(wm + mi * 16 + l16) * 32 + quad * 8];
#pragma unroll
        for (int ni = 0; ni < 4; ++ni)
            bf[ni] = *(const short8*)&Bs[(wn + ni * 16 + l16) * 32 + quad * 8];
#pragma unroll
        for (int mi = 0; mi < 4; ++mi)
#pragma unroll
            for (int ni = 0; ni < 4; ++ni)
                acc[mi][ni] = __builtin_amdgcn_mfma_f32_16x16x32_bf16(
                    af[mi], bf[ni], acc[mi][ni], 0, 0, 0);
    }

    // ---- epilogue: wave-private LDS transpose, then coalesced stores ----
    __syncthreads();
    ushort_t* Ep = lds + w * 4608;         // 64 rows x 72 pitch

    const int mat = n0 >> 10;              // 0=q 1=k 2=v
    const int cb  = (n0 & 1023) + wn;
    const int h   = cb >> 6;
    ushort_t* dst = (mat == 0) ? q_ws : (mat == 1) ? k_ws : v_ws;
    const float sc = (mat == 0) ? SCALE_QL2 : 1.0f;

#pragma unroll
    for (int mi = 0; mi < 4; ++mi)
#pragma unroll
        for (int ni = 0; ni < 4; ++ni)
#pragma unroll
            for (int r = 0; r < 4; ++r)
                Ep[(mi * 16 + quad * 4 + r) * 72 + ni * 16 + l16] =
                    f2bf(acc[mi][ni][r] * sc);
    // wave-private region: lgkmcnt dependency only

    const int rq = lane >> 3;
    const int c8 = (lane & 7) * 8;
#pragma unroll
    for (int p = 0; p < 8; ++p) {
        const int row = p * 8 + rq;
        const uint4 val = *(const uint4*)&Ep[row * 72 + c8];
        const int m = m0 + wm + row;
        const int t = m >> 1, b = m & 1;
        *(uint4*)&dst[((size_t)(b * H_DIM + h) * T_DIM + t) * D_DIM + c8] = val;
    }
}

// ---------------------------------------------------------------------------
// V transpose: (bh, t, d) bf16 -> (bh, d, t) bf16, 64x64 tiles.
// Kept separate: fusing into qkv measured net-slower (see ledger).
// ---------------------------------------------------------------------------
__global__ __launch_bounds__(256) void v_transpose(
    const ushort_t* __restrict__ vn, ushort_t* __restrict__ vt)
{
    __shared__ ushort_t tile[64][72];
    const int tid = threadIdx.x;
    const int t0  = blockIdx.x * 64;
    const int bh  = blockIdx.y;
    const int r   = tid >> 3;
    const int c   = (tid & 7) * 8;
#pragma unroll
    for (int i = 0; i < 2; ++i)
        *(uint4*)&tile[r + i * 32][c] =
            *(const uint4*)&vn[((size_t)bh * T_DIM + t0 + r + i * 32) * D_DIM + c];
    __syncthreads();
#pragma unroll
    for (int i = 0; i < 2; ++i) {
        const int rd = r + i * 32;       // d
        ushort_t o[8];
#pragma unroll
        for (int j = 0; j < 8; ++j) o[j] = tile[c + j][rd];
        *(uint4*)&vt[((size_t)bh * D_DIM + rd) * T_DIM + t0 + c] = *(uint4*)o;
    }
}

// ---------------------------------------------------------------------------
// MFMA flash attention, 32x32x16 shape, swapped QK^T, in-register softmax.
// Measured: 55.6 us, 96 VGPR, zero spill, 0 bank conflicts (round 3).
//  - mfma(K,Q) gives S^T with q-row = lane&31 -> P is LANE-LOCAL; repack to
//    PV A-fragments via 16 v_perm_b32 + 8 v_permlane32_swap_b32.
//  - 32 q-rows/wave: K/V frag reads amortized 2x vs 16x16.
//  - row sums via ones-MFMA on the exact bf16 P fragments.
//  - q pre-scaled by log2e at qkv: P = exp2(S) directly, max-free.
//  - grid: x = bh, y = q-tile(128). XCD i gets only bh === i (mod 8): 2 MB
//    K/V per XCD L2. (Axis swap measured FETCH 12->70 MB. Keep.)
// ---------------------------------------------------------------------------
__global__ __launch_bounds__(256) void attn_mfma(
    const ushort_t* __restrict__ q, const ushort_t* __restrict__ k,
    const ushort_t* __restrict__ v, ushort_t* __restrict__ ctx)
{
    __shared__ ushort_t Ks [64][72];
    __shared__ ushort_t Vts[64][72];

    const int tid  = threadIdx.x;
    const int bh   = blockIdx.x;
    const int q0   = blockIdx.y * 128;
    const int w    = tid >> 6;
    const int lane = tid & 63;
    const int l32  = lane & 31;
    const int hi   = lane >> 5;

    const int r0 = tid >> 3,         c80 = (tid & 7) * 8;
    const int r1 = r0 + 32;
    const ushort_t* kbase = k + (size_t)bh * T_DIM * D_DIM;
    const ushort_t* vbase = v + (size_t)bh * D_DIM * T_DIM;

    // Q in registers: lane l32 = q-row (q0+32w+l32), hi selects d-chunk of 8.
    short8 qreg[4];
    {
        const ushort_t* qrow =
            q + ((size_t)bh * T_DIM + q0 + 32 * w + l32) * D_DIM + hi * 8;
#pragma unroll
        for (int s = 0; s < 4; ++s)
            qreg[s] = *(const short8*)(qrow + s * 16);
    }

    // constant all-ones B fragment (bf16 1.0 = 0x3F80)
    short8 vones;
#pragma unroll
    for (int j = 0; j < 8; ++j) vones[j] = (short)0x3F80;

    f32x16 O0 = {}, O1 = {};      // O[q=32][d=64]: d-tiles 0/1
    f32x16 Osum = {};             // row sums of bf16(P) via ones-MFMA

    // prefetch tile 0; pointers advance by constant strides
    const ushort_t* kp0 = kbase + (size_t)r0 * D_DIM + c80;
    const ushort_t* kp1 = kbase + (size_t)r1 * D_DIM + c80;
    const ushort_t* vp0 = vbase + (size_t)r0 * T_DIM + c80;
    const ushort_t* vp1 = vbase + (size_t)r1 * T_DIM + c80;
    uint4 kr0 = *(const uint4*)kp0;  kp0 += 64 * D_DIM;
    uint4 kr1 = *(const uint4*)kp1;  kp1 += 64 * D_DIM;
    uint4 vr0 = *(const uint4*)vp0;  vp0 += 64;
    uint4 vr1 = *(const uint4*)vp1;  vp1 += 64;

    for (int kt = 0; kt < 32; ++kt) {
        __syncthreads();
        *(uint4*)&Ks[r0][c80]  = kr0;
        *(uint4*)&Ks[r1][c80]  = kr1;
        *(uint4*)&Vts[r0][c80] = vr0;
        *(uint4*)&Vts[r1][c80] = vr1;
        if (kt + 1 < 32) {
            kr0 = *(const uint4*)kp0;  kp0 += 64 * D_DIM;
            kr1 = *(const uint4*)kp1;  kp1 += 64 * D_DIM;
            vr0 = *(const uint4*)vp0;  vp0 += 64;
            vr1 = *(const uint4*)vp1;  vp1 += 64;
        }
        __syncthreads();

        // S^T = K · Q : A = K-tile rows (lane&31 = k-pos), B = Q (in regs).
        // C layout: col = lane&31 = q-row (lane-local), row = k-pos.
        f32x16 st0 = {}, st1 = {};
        __builtin_amdgcn_s_setprio(1);
#pragma unroll
        for (int s = 0; s < 4; ++s) {
            const short8 ak0 = *(const short8*)&Ks[l32]     [s * 16 + hi * 8];
            const short8 ak1 = *(const short8*)&Ks[32 + l32][s * 16 + hi * 8];
            st0 = __builtin_amdgcn_mfma_f32_32x32x16_bf16(ak0, qreg[s], st0, 0, 0, 0);
            st1 = __builtin_amdgcn_mfma_f32_32x32x16_bf16(ak1, qreg[s], st1, 0, 0, 0);
        }
        __builtin_amdgcn_s_setprio(0);

        // P = exp2(S^T), packed to bf16 pairs (truncation via v_perm_b32).
        unsigned wpk0[8], wpk1[8];
#pragma unroll
        for (int i = 0; i < 8; ++i) {
            const float a0 = EXP2(st0[2 * i]);
            const float a1 = EXP2(st0[2 * i + 1]);
            const float b0 = EXP2(st1[2 * i]);
            const float b1 = EXP2(st1[2 * i + 1]);
            wpk0[i] = __builtin_amdgcn_perm(
                __builtin_bit_cast(unsigned, a1),
                __builtin_bit_cast(unsigned, a0), 0x07060302u);
            wpk1[i] = __builtin_amdgcn_perm(
                __builtin_bit_cast(unsigned, b1),
                __builtin_bit_cast(unsigned, b0), 0x07060302u);
        }

        // cross-half exchange -> PV A-fragments ap[s], k = 16s+8hi+{0..7}
        short8 ap[4];
#pragma unroll
        for (int pr = 0; pr < 2; ++pr) {
            unsigned x0 = wpk0[4 * pr + 0], y0 = wpk0[4 * pr + 2];
            unsigned x1 = wpk0[4 * pr + 1], y1 = wpk0[4 * pr + 3];
            asm("v_permlane32_swap_b32 %0, %1" : "+v"(x0), "+v"(y0));
            asm("v_permlane32_swap_b32 %0, %1" : "+v"(x1), "+v"(y1));
            uint4 fw = {x0, x1, y0, y1};
            ap[pr] = __builtin_bit_cast(short8, fw);

            unsigned u0 = wpk1[4 * pr + 0], z0 = wpk1[4 * pr + 2];
            unsigned u1 = wpk1[4 * pr + 1], z1 = wpk1[4 * pr + 3];
            asm("v_permlane32_swap_b32 %0, %1" : "+v"(u0), "+v"(z0));
            asm("v_permlane32_swap_b32 %0, %1" : "+v"(u1), "+v"(z1));
            uint4 fw1 = {u0, u1, z0, z1};
            ap[2 + pr] = __builtin_bit_cast(short8, fw1);
        }

        // PV + row sums. B = V^T rows (lane&31 = d), hi selects k-chunk.
        __builtin_amdgcn_s_setprio(1);
#pragma unroll
        for (int s = 0; s < 4; ++s) {
            Osum = __builtin_amdgcn_mfma_f32_32x32x16_bf16(ap[s], vones, Osum, 0, 0, 0);
            const short8 bv0 = *(const short8*)&Vts[l32]     [s * 16 + hi * 8];
            const short8 bv1 = *(const short8*)&Vts[32 + l32][s * 16 + hi * 8];
            O0 = __builtin_amdgcn_mfma_f32_32x32x16_bf16(ap[s], bv0, O0, 0, 0, 0);
            O1 = __builtin_amdgcn_mfma_f32_32x32x16_bf16(ap[s], bv1, O1, 0, 0, 0);
        }
        __builtin_amdgcn_s_setprio(0);
    }

    // epilogue: O row = (reg&3)+8*(reg>>2)+4*hi, col = l32 = d (dt*32+l32)
    const int b = bh >> 4;
    const int h = bh & 15;
#pragma unroll
    for (int reg = 0; reg < 16; ++reg) {
        const int qrel = (reg & 3) + 8 * (reg >> 2) + 4 * hi;
        const float inv = 1.0f / Osum[reg];
        const int row = q0 + 32 * w + qrel;
        const size_t base = ((size_t)row * B_DIM + b) * C_DIM + h * 64 + l32;
        ctx[base]      = f2bf(O0[reg] * inv);
        ctx[base + 32] = f2bf(O1[reg] * inv);
    }
}

// ---------------------------------------------------------------------------
// Output projection, bf16 MFMA: out[m,n] = ctx[m,k] @ wo_t[n,k]^T + bo[n].
// ---------------------------------------------------------------------------
__global__ __launch_bounds__(256) void out_mfma(
    const ushort_t* __restrict__ ctx, const ushort_t* __restrict__ wot,
    const float* __restrict__ bo, float* __restrict__ out)
{
    __shared__ ushort_t As[128 * 32];
    __shared__ ushort_t Bs[64 * 32];

    const int tid  = threadIdx.x;
    const int n0   = blockIdx.x * 64;
    const int m0   = blockIdx.y * 128;
    const int w    = tid >> 6;
    const int lane = tid & 63;
    const int l16  = lane & 15;
    const int quad = lane >> 4;
    const int wm   = (w >> 1) * 64;
    const int wn   = (w & 1) * 32;

    const int o0 = tid * 8, o1 = o0 + 2048;
    const ushort_t* a0 = ctx + (size_t)(m0 + (o0 >> 5)) * C_DIM + (o0 & 31);
    const ushort_t* a1 = ctx + (size_t)(m0 + (o1 >> 5)) * C_DIM + (o1 & 31);
    const ushort_t* b0 = wot + (size_t)(n0 + (o0 >> 5)) * C_DIM + (o0 & 31);

    f32x4 acc[4][2] = {};

    for (int k0 = 0; k0 < C_DIM; k0 += 32) {
        __syncthreads();
        gl_lds16(a0 + k0, As + o0);
        gl_lds16(a1 + k0, As + o1);
        gl_lds16(b0 + k0, Bs + o0);
        __syncthreads();

        short8 af[4], bf[2];
#pragma unroll
        for (int mi = 0; mi < 4; ++mi)
            af[mi] = *(const short8*)&As[(wm + mi * 16 + l16) * 32 + quad * 8];
#pragma unroll
        for (int ni = 0; ni < 2; ++ni)
            bf[ni] = *(const short8*)&Bs[(wn + ni * 16 + l16) * 32 + quad * 8];
#pragma unroll
        for (int mi = 0; mi < 4; ++mi)
#pragma unroll
            for (int ni = 0; ni < 2; ++ni)
                acc[mi][ni] = __builtin_amdgcn_mfma_f32_16x16x32_bf16(
                    af[mi], bf[ni], acc[mi][ni], 0, 0, 0);
    }

#pragma unroll
    for (int ni = 0; ni < 2; ++ni) {
        const int n = n0 + wn + ni * 16 + l16;
        const float bias = bo[n];
#pragma unroll
        for (int mi = 0; mi < 4; ++mi) {
            const int mb = m0 + wm + mi * 16 + quad * 4;
#pragma unroll
            for (int r = 0; r < 4; ++r)
                out[(size_t)(mb + r) * C_DIM + n] = acc[mi][ni][r] + bias;
        }
    }
}

extern "C" void kernel_launch(void* const* d_in, const int* in_sizes, int n_in,
                              void* d_out, int out_size, void* d_ws, size_t ws_size,
                              hipStream_t stream)
{
    const float* x  = (const float*)d_in[0];
    const float* wq = (const float*)d_in[1];
    const float* wk = (const float*)d_in[2];
    const float* wv = (const float*)d_in[3];
    const float* wo = (const float*)d_in[4];
    const float* bo = (const float*)d_in[5];
    float* out = (float*)d_out;

    const size_t CC  = (size_t)C_DIM * C_DIM;          // 1.05M
    const size_t MC  = (size_t)M_DIM * C_DIM;          // 4.19M
    ushort_t* xb     = (ushort_t*)d_ws;
    ushort_t* wqkv_t = xb + MC;
    ushort_t* wo_t   = wqkv_t + 3 * CC;
    ushort_t* q_ws   = wo_t + CC;
    ushort_t* k_ws   = q_ws + MC;
    ushort_t* v_nat  = k_ws + MC;
    ushort_t* v_t    = v_nat + MC;
    ushort_t* ctx    = v_t + MC;                        // total ~58.7 MB

    hipLaunchKernelGGL(prep, dim3(16, 16, 5), dim3(256), 0, stream,
                       x, wq, wk, wv, wo, xb, wqkv_t, wo_t);
    hipLaunchKernelGGL(qkv_mfma, dim3(24, 32), dim3(256), 0, stream,
                       xb, wqkv_t, q_ws, k_ws, v_nat);
    hipLaunchKernelGGL(v_transpose, dim3(32, 32), dim3(256), 0, stream,
                       v_nat, v_t);
    hipLaunchKernelGGL(attn_mfma, dim3(32, 16), dim3(256), 0, stream,
                       q_ws, k_ws, v_t, ctx);
    hipLaunchKernelGGL(out_mfma, dim3(16, 32), dim3(256), 0, stream,
                       ctx, wo_t, bo, out);
}